// Round 20
// baseline (30.252 us; speedup 1.0000x reference)
//
#include <hip/hip_runtime.h>
#include <hip/hip_bf16.h>

// CAM: out = (q @ k^T) @ v + v  ==  q @ (k^T @ v) + v.   S[b] = k^T v is 49x49.
// TWO kernels (R19 = R18 + Spart halving + NT stores):
//   ktv : 512 blocks x 512 thr (8 waves = 2 layers x 4 quadrants), split=4.
//         Streaming MFMA (A=V,B=K -> S^T), LDS pairwise layer-reduce, bf16
//         [49][64] partial per block (3.2 MB total), u16x8 flat stores.
//   qs  : R18-proven core, SPLIT=4 reduce, nontemporal Og stores (out never
//         re-read -> preserve L2 for V/q/Spart).
//   Swizzles matched: batch b -> XCD floor(b/16) in BOTH kernels.
// Fusion dead (R12/R14). XCD affinity proven (R17: -5.9us).

#define BATCH 128
#define CH    1024
#define NN    49
#define SPLIT 4
#define SROW  64                 // Spart cols per row
#define SSZ   (NN * SROW)        // 3136 u16 = 6272 B per partial
#define LDQT  56                 // bf16 row stride of Qt: 112 B
#define LDST  72                 // bf16 row stride of Sl : 144 B

typedef short  bf16x8 __attribute__((ext_vector_type(8)));
typedef float  f32x16 __attribute__((ext_vector_type(16)));
typedef unsigned short u16x8 __attribute__((ext_vector_type(8)));

__device__ __forceinline__ short f2bf(float x) {
  return __builtin_bit_cast(short, __float2bfloat16(x));   // RNE
}
__device__ __forceinline__ float bf2f(unsigned short h) {
  return __builtin_bit_cast(float, ((unsigned)h) << 16);
}

// -------- Kernel 1: Spart[b,s] = bf16( V-chunk^T x K-chunk ) = S^T-part -----
// grid 512; swizzle (bi&7)*64+bi>>3 -> batch b on XCD floor(b/16) (matches qs)
__global__ __launch_bounds__(512) void ktv_kernel(
    const float* __restrict__ Kg, const float* __restrict__ Vg,
    unsigned short* __restrict__ Spart) {
  const int blk  = (blockIdx.x & 7) * 64 + (blockIdx.x >> 3);
  const int b    = blk >> 2;
  const int s    = blk & 3;
  const int tid  = threadIdx.x;
  const int wv   = tid >> 6;
  const int lane = tid & 63;
  const int g    = lane >> 5;
  const int ln   = lane & 31;
  const int layer = wv >> 2;             // 2 channel-layers of 128 ch
  const int quad  = wv & 3;
  const int i0   = (quad >> 1) * 32;     // S^T row quadrant (V position)
  const int j0   = (quad & 1)  * 32;     // S^T col quadrant (K position)
  const int rowA = min(i0 + ln, NN - 1); // clamp: dup loads, junk discarded
  const int rowB = min(j0 + ln, NN - 1);

  __shared__ __align__(16) float red[4][32 * 32];   // 16 KB quadrant tiles

  const size_t cbase = ((size_t)b * CH + (size_t)s * 256 + layer * 128) * NN;
  const float* Va = Vg + cbase + (size_t)(g * 8) * NN + rowA;   // A = V
  const float* Kb = Kg + cbase + (size_t)(g * 8) * NN + rowB;   // B = K

  f32x16 acc;
  #pragma unroll
  for (int r = 0; r < 16; ++r) acc[r] = 0.f;

  #pragma unroll 4
  for (int kc = 0; kc < 8; ++kc) {       // 8 chunks x 16 channels = 128 ch
    const float* va = Va + (size_t)kc * 16 * NN;
    const float* kb = Kb + (size_t)kc * 16 * NN;
    float vx[8], kx[8];
    #pragma unroll
    for (int e = 0; e < 8; ++e) { vx[e] = va[e * NN]; kx[e] = kb[e * NN]; }
    bf16x8 av, bk;
    #pragma unroll
    for (int e = 0; e < 8; ++e) { av[e] = f2bf(vx[e]); bk[e] = f2bf(kx[e]); }
    acc = __builtin_amdgcn_mfma_f32_32x32x16_bf16(av, bk, acc, 0, 0, 0);
  }

  // C/D: col = lane&31, row-in-quad = (r&3)+8*(r>>2)+4*g  [m74/m101]
  if (layer == 0) {
    #pragma unroll
    for (int r = 0; r < 16; ++r) {
      const int arel = (r & 3) + 8 * (r >> 2) + 4 * g;
      red[quad][arel * 32 + ln] = acc[r];          // lanes: distinct banks
    }
  }
  __syncthreads();
  if (layer == 1) {
    #pragma unroll
    for (int r = 0; r < 16; ++r) {
      const int arel = (r & 3) + 8 * (r >> 2) + 4 * g;
      red[quad][arel * 32 + ln] += acc[r];
    }
  }
  __syncthreads();

  // convert + flat u16x8 stores of rows a<49 (junk rows 49..63 dropped)
  unsigned short* Sp = Spart + (size_t)blk * SSZ;
  if (tid < SSZ / 8) {
    const int a = tid >> 3, c0 = (tid & 7) * 8;
    const int q = ((a >= 32) << 1) | (c0 >= 32);
    const float* src = &red[q][(a & 31) * 32 + (c0 & 31)];
    u16x8 o;
    #pragma unroll
    for (int k = 0; k < 8; ++k) o[k] = (unsigned short)f2bf(src[k]);
    *(u16x8*)&Sp[a * SROW + c0] = o;
  }
}

// -------- Kernel 2: out[128-row tile] = q @ S + v ---------------------------
__global__ __launch_bounds__(256) void qs_kernel(
    const float* __restrict__ Qg, const float* __restrict__ Vg,
    const unsigned short* __restrict__ Spart, float* __restrict__ Og) {
  const int blk  = (blockIdx.x & 7) * 128 + (blockIdx.x >> 3);  // R17-proven
  const int b    = blk >> 3;
  const int pr   = blk & 7;
  const int tid  = threadIdx.x;
  const int wv   = tid >> 6;
  const int lane = tid & 63;
  const int g    = lane >> 5;
  const int ln   = lane & 31;
  const int i0   = (wv >> 1) * 32;
  const int j0   = (wv & 1)  * 32;

  __shared__ __align__(16) unsigned short Qt[128 * LDQT];  // 14.3 KB
  __shared__ __align__(16) unsigned short Sl[64 * LDST];   //  9.2 KB

  const size_t qbase = ((size_t)b * CH + (size_t)pr * 128) * NN;

  // stage 128 q-rows bf16 via float4 loads (16-B aligned; 1 KB/wave/instr)
  for (int fq = tid; fq < 128 * NN / 4; fq += 256) {
    const float4 qv = *(const float4*)&Qg[qbase + 4 * fq];
    const int f0 = 4 * fq;
    #pragma unroll
    for (int k = 0; k < 4; ++k) {
      const int f = f0 + k;
      const int r = f / NN, m = f - r * NN;
      Qt[r * LDQT + m] = (unsigned short)f2bf(((const float*)&qv)[k]);
    }
  }

  // reduce 4 bf16 partials -> Sl[n][m], n<49 (L2-hot via same-XCD swizzle)
  {
    const unsigned short* sp = Spart + (size_t)(b * SPLIT) * SSZ;
    for (int e8 = tid; e8 < SSZ / 8; e8 += 256) {
      float v[8];
      #pragma unroll
      for (int k = 0; k < 8; ++k) v[k] = 0.f;
      #pragma unroll
      for (int s = 0; s < SPLIT; ++s) {
        const u16x8 w = *(const u16x8*)&sp[(size_t)s * SSZ + 8 * e8];
        #pragma unroll
        for (int k = 0; k < 8; ++k) v[k] += bf2f(w[k]);
      }
      const int n = e8 >> 3, m0 = (e8 & 7) * 8;
      u16x8 o;
      #pragma unroll
      for (int k = 0; k < 8; ++k) o[k] = (unsigned short)f2bf(v[k]);
      *(u16x8*)&Sl[n * LDST + m0] = o;            // 16-B aligned
    }
  }
  __syncthreads();

  const unsigned short* qt0 = &Qt[(i0 + ln) * LDQT];        // tile 0 row
  const unsigned short* qt1 = &Qt[(64 + i0 + ln) * LDQT];   // tile 1 row
  const unsigned short* slb = &Sl[(j0 + ln) * LDST];        // S^T row j

  f32x16 acc0, acc1;
  #pragma unroll
  for (int r = 0; r < 16; ++r) { acc0[r] = 0.f; acc1[r] = 0.f; }

  #pragma unroll
  for (int kc = 0; kc < 3; ++kc) {       // m0 <= 47: all fragment m's valid
    const int m0 = kc * 16 + g * 8;
    const bf16x8 a0 = *(const bf16x8*)&qt0[m0];    // one ds_read_b128
    const bf16x8 a1 = *(const bf16x8*)&qt1[m0];
    const bf16x8 bh = *(const bf16x8*)&slb[m0];
    acc0 = __builtin_amdgcn_mfma_f32_32x32x16_bf16(a0, bh, acc0, 0, 0, 0);
    acc1 = __builtin_amdgcn_mfma_f32_32x32x16_bf16(a1, bh, acc1, 0, 0, 0);
  }
  {                                      // tail: only m=48 real; S cols m>=49
    const int m0 = 48 + g * 8;           // finite junk -> 0*finite = 0
    bf16x8 a0, a1;
    #pragma unroll
    for (int e = 0; e < 8; ++e) { a0[e] = 0; a1[e] = 0; }
    a0[0] = (g == 0) ? (short)qt0[48] : (short)0;
    a1[0] = (g == 0) ? (short)qt1[48] : (short)0;
    const bf16x8 bh = *(const bf16x8*)&slb[m0];
    acc0 = __builtin_amdgcn_mfma_f32_32x32x16_bf16(a0, bh, acc0, 0, 0, 0);
    acc1 = __builtin_amdgcn_mfma_f32_32x32x16_bf16(a1, bh, acc1, 0, 0, 0);
  }

  // epilogue: nontemporal stores (out never re-read; keep L2 for V/q/Spart)
  const int j = j0 + ln;
  if (j < NN) {
    #pragma unroll
    for (int r = 0; r < 16; ++r) {
      const int i = i0 + (r & 3) + 8 * (r >> 2) + 4 * g;
      const size_t o0 = qbase + (size_t)i * NN + j;
      const size_t o1 = qbase + (size_t)(64 + i) * NN + j;
      __builtin_nontemporal_store(acc0[r] + Vg[o0], &Og[o0]);
      __builtin_nontemporal_store(acc1[r] + Vg[o1], &Og[o1]);
    }
  }
}

extern "C" void kernel_launch(void* const* d_in, const int* in_sizes, int n_in,
                              void* d_out, int out_size, void* d_ws, size_t ws_size,
                              hipStream_t stream) {
  (void)in_sizes; (void)n_in; (void)out_size; (void)ws_size;
  const float* v1 = (const float*)d_in[0];
  const float* q1 = (const float*)d_in[1];
  const float* k1 = (const float*)d_in[2];
  float* out = (float*)d_out;

  unsigned short* spart = (unsigned short*)d_ws;   // 512 * 6272 B = 3.2 MB

  ktv_kernel<<<dim3(BATCH * SPLIT), dim3(512), 0, stream>>>(k1, v1, spart);
  qs_kernel<<<dim3(BATCH * 8), dim3(256), 0, stream>>>(q1, v1, spart, out);
}

// Round 21
// 28.264 us; speedup vs baseline: 1.0703x; 1.0703x over previous
//
#include <hip/hip_runtime.h>
#include <hip/hip_bf16.h>

// CAM: out = (q @ k^T) @ v + v  ==  q @ (k^T @ v) + v.   S[b] = k^T v is 49x49.
// R20 = exact revert to R18 (proven best: 28.2us). R19's bundle (split=4 +
// 512-thr ktv reduce, NT stores, retuned swizzle) regressed to 30.3us:
// two-barrier reduce serialized ktv's tail; NT stores defeated L2 write-merge.
//   ktv : streaming MFMA (A=V,B=K -> S^T direct), split=8, batch->XCD swizzle,
//         Spart bf16 [49][64] via LDS bounce -> flat u16x8 stores.
//   qs  : float4 Q staging -> bf16 Qt LDS; reduce 8 bf16 partials (u16x8,
//         L2-hot via same-XCD swizzle) -> Sl LDS; b128 A/B frags; zero-A tail;
//         coalesced epilogue out = acc + v.
// Fusion dead (R12/R14: cross-XCD coherent ~0.5 TB/s). Swizzle proven (R17).

#define BATCH 128
#define CH    1024
#define NN    49
#define SPLIT 8
#define SROW  64                 // Spart cols per row
#define SSZ   (NN * SROW)        // 3136 u16 = 6272 B per partial (16-mult)
#define LDQT  56                 // bf16 row stride of Qt: 112 B
#define LDST  72                 // bf16 row stride of Sl : 144 B

typedef short  bf16x8 __attribute__((ext_vector_type(8)));
typedef float  f32x16 __attribute__((ext_vector_type(16)));
typedef unsigned short u16x8 __attribute__((ext_vector_type(8)));

__device__ __forceinline__ short f2bf(float x) {
  return __builtin_bit_cast(short, __float2bfloat16(x));   // RNE
}
__device__ __forceinline__ float bf2f(unsigned short h) {
  return __builtin_bit_cast(float, ((unsigned)h) << 16);
}
// bijective for 1024 blocks; all 8 blocks of a batch share one XCD (R17)
__device__ __forceinline__ int xcd_swizzle(int wgid) {
  return (wgid & 7) * 128 + (wgid >> 3);
}

// -------- Kernel 1: Spart[b,s] = bf16( V-chunk^T x K-chunk ) = S^T-part -----
__global__ __launch_bounds__(256) void ktv_kernel(
    const float* __restrict__ Kg, const float* __restrict__ Vg,
    unsigned short* __restrict__ Spart) {
  const int blk  = xcd_swizzle(blockIdx.x);  // 1024 = 128 batches x 8 splits
  const int b    = blk >> 3;
  const int s    = blk & 7;
  const int tid  = threadIdx.x;
  const int wv   = tid >> 6;
  const int lane = tid & 63;
  const int g    = lane >> 5;
  const int ln   = lane & 31;
  const int i0   = (wv >> 1) * 32;       // S^T row quadrant (V position)
  const int j0   = (wv & 1)  * 32;       // S^T col quadrant (K position)
  const int rowA = min(i0 + ln, NN - 1); // clamp: dup loads, junk discarded
  const int rowB = min(j0 + ln, NN - 1);

  __shared__ __align__(16) unsigned short Ot[SSZ];   // 6.3 KB bounce tile

  const size_t cbase = ((size_t)b * CH + (size_t)s * 128) * NN;
  const float* Va = Vg + cbase + (size_t)(g * 8) * NN + rowA;   // A = V
  const float* Kb = Kg + cbase + (size_t)(g * 8) * NN + rowB;   // B = K

  f32x16 acc;
  #pragma unroll
  for (int r = 0; r < 16; ++r) acc[r] = 0.f;

  #pragma unroll 4
  for (int kc = 0; kc < 8; ++kc) {       // 8 chunks x 16 channels = 128 ch
    const float* va = Va + (size_t)kc * 16 * NN;
    const float* kb = Kb + (size_t)kc * 16 * NN;
    float vx[8], kx[8];
    #pragma unroll
    for (int e = 0; e < 8; ++e) { vx[e] = va[e * NN]; kx[e] = kb[e * NN]; }
    bf16x8 av, bk;
    #pragma unroll
    for (int e = 0; e < 8; ++e) { av[e] = f2bf(vx[e]); bk[e] = f2bf(kx[e]); }
    acc = __builtin_amdgcn_mfma_f32_32x32x16_bf16(av, bk, acc, 0, 0, 0);
  }

  // C/D: col = lane&31, row = (r&3)+8*(r>>2)+4*g  [m74/m101, HW-validated]
  const int c = j0 + ln;
  #pragma unroll
  for (int r = 0; r < 16; ++r) {
    const int a = i0 + (r & 3) + 8 * (r >> 2) + 4 * g;
    if (a < NN) Ot[a * SROW + c] = (unsigned short)f2bf(acc[r]);  // 2-way ok
  }
  __syncthreads();

  // flat u16x8 stores: 1 KB/wave/instr, ~1.5 instr/thread
  unsigned short* Sp = Spart + (size_t)blk * SSZ;
  for (int e8 = tid; e8 < SSZ / 8; e8 += 256)
    *(u16x8*)&Sp[8 * e8] = *(const u16x8*)&Ot[8 * e8];
}

// -------- Kernel 2: out[128-row tile] = q @ S + v ---------------------------
__global__ __launch_bounds__(256) void qs_kernel(
    const float* __restrict__ Qg, const float* __restrict__ Vg,
    const unsigned short* __restrict__ Spart, float* __restrict__ Og) {
  const int blk  = xcd_swizzle(blockIdx.x);  // 1024 = 128 batches x 8 tiles
  const int b    = blk >> 3;
  const int pr   = blk & 7;
  const int tid  = threadIdx.x;
  const int wv   = tid >> 6;
  const int lane = tid & 63;
  const int g    = lane >> 5;
  const int ln   = lane & 31;
  const int i0   = (wv >> 1) * 32;
  const int j0   = (wv & 1)  * 32;

  __shared__ __align__(16) unsigned short Qt[128 * LDQT];  // 14.3 KB
  __shared__ __align__(16) unsigned short Sl[64 * LDST];   //  9.2 KB

  const size_t qbase = ((size_t)b * CH + (size_t)pr * 128) * NN;

  // stage 128 q-rows bf16 via float4 loads (16-B aligned; 1 KB/wave/instr)
  for (int fq = tid; fq < 128 * NN / 4; fq += 256) {
    const float4 qv = *(const float4*)&Qg[qbase + 4 * fq];
    const int f0 = 4 * fq;
    #pragma unroll
    for (int k = 0; k < 4; ++k) {
      const int f = f0 + k;
      const int r = f / NN, m = f - r * NN;
      Qt[r * LDQT + m] = (unsigned short)f2bf(((const float*)&qv)[k]);
    }
  }

  // reduce 8 bf16 partials -> Sl[n][m], n<49 (rows 49-63 unused->discarded js)
  {
    const unsigned short* sp = Spart + (size_t)(b * SPLIT) * SSZ;
    for (int e8 = tid; e8 < SSZ / 8; e8 += 256) {
      float v[8];
      #pragma unroll
      for (int k = 0; k < 8; ++k) v[k] = 0.f;
      #pragma unroll
      for (int s = 0; s < SPLIT; ++s) {
        const u16x8 w = *(const u16x8*)&sp[(size_t)s * SSZ + 8 * e8];
        #pragma unroll
        for (int k = 0; k < 8; ++k) v[k] += bf2f(w[k]);
      }
      const int n = e8 >> 3, m0 = (e8 & 7) * 8;   // n in 0..48, m0 in 0..56
      u16x8 o;
      #pragma unroll
      for (int k = 0; k < 8; ++k) o[k] = (unsigned short)f2bf(v[k]);
      *(u16x8*)&Sl[n * LDST + m0] = o;            // 16-B aligned
    }
  }
  __syncthreads();

  const unsigned short* qt0 = &Qt[(i0 + ln) * LDQT];        // tile 0 row
  const unsigned short* qt1 = &Qt[(64 + i0 + ln) * LDQT];   // tile 1 row
  const unsigned short* slb = &Sl[(j0 + ln) * LDST];        // S^T row j

  f32x16 acc0, acc1;
  #pragma unroll
  for (int r = 0; r < 16; ++r) { acc0[r] = 0.f; acc1[r] = 0.f; }

  #pragma unroll
  for (int kc = 0; kc < 3; ++kc) {       // m0 <= 47: all fragment m's valid
    const int m0 = kc * 16 + g * 8;
    const bf16x8 a0 = *(const bf16x8*)&qt0[m0];    // one ds_read_b128
    const bf16x8 a1 = *(const bf16x8*)&qt1[m0];
    const bf16x8 bh = *(const bf16x8*)&slb[m0];
    acc0 = __builtin_amdgcn_mfma_f32_32x32x16_bf16(a0, bh, acc0, 0, 0, 0);
    acc1 = __builtin_amdgcn_mfma_f32_32x32x16_bf16(a1, bh, acc1, 0, 0, 0);
  }
  {                                      // tail: only m=48 real; S cols m>=49
    const int m0 = 48 + g * 8;           // are finite junk -> 0*finite = 0
    bf16x8 a0, a1;
    #pragma unroll
    for (int e = 0; e < 8; ++e) { a0[e] = 0; a1[e] = 0; }
    a0[0] = (g == 0) ? (short)qt0[48] : (short)0;
    a1[0] = (g == 0) ? (short)qt1[48] : (short)0;
    const bf16x8 bh = *(const bf16x8*)&slb[m0];
    acc0 = __builtin_amdgcn_mfma_f32_32x32x16_bf16(a0, bh, acc0, 0, 0, 0);
    acc1 = __builtin_amdgcn_mfma_f32_32x32x16_bf16(a1, bh, acc1, 0, 0, 0);
  }

  // epilogue: all 64 rows/tile valid; guard col j < 49; coalesced per r
  const int j = j0 + ln;
  if (j < NN) {
    #pragma unroll
    for (int r = 0; r < 16; ++r) {
      const int i = i0 + (r & 3) + 8 * (r >> 2) + 4 * g;
      const size_t o0 = qbase + (size_t)i * NN + j;
      const size_t o1 = qbase + (size_t)(64 + i) * NN + j;
      Og[o0] = acc0[r] + Vg[o0];
      Og[o1] = acc1[r] + Vg[o1];
    }
  }
}

extern "C" void kernel_launch(void* const* d_in, const int* in_sizes, int n_in,
                              void* d_out, int out_size, void* d_ws, size_t ws_size,
                              hipStream_t stream) {
  (void)in_sizes; (void)n_in; (void)out_size; (void)ws_size;
  const float* v1 = (const float*)d_in[0];
  const float* q1 = (const float*)d_in[1];
  const float* k1 = (const float*)d_in[2];
  float* out = (float*)d_out;

  unsigned short* spart = (unsigned short*)d_ws;   // 1024 * 6272 B = 6.42 MB

  ktv_kernel<<<dim3(BATCH * SPLIT), dim3(256), 0, stream>>>(k1, v1, spart);
  qs_kernel<<<dim3(BATCH * 8), dim3(256), 0, stream>>>(q1, v1, spart, out);
}